// Round 1
// baseline (44.223 us; speedup 1.0000x reference)
//
#include <hip/hip_runtime.h>
#include <hip/hip_bf16.h>
#include <math.h>

// Problem constants (from reference setup_inputs)
#define B_ROWS 256
#define D_IN   128
#define D_OUT  256
#define M_LEN  4096
#define BETA   50.0f

// out layout (f32): loss[256] | mem_out[4096*256] | md_out[4096*128]
#define OFF_MEM  (B_ROWS)
#define OFF_MD   (B_ROWS + M_LEN * D_OUT)

// ---------------------------------------------------------------------------
// K0: copy memory -> mem_out, mem_data -> md_out, init loss to +inf bits
// ---------------------------------------------------------------------------
__global__ void k_init_copy(const float4* __restrict__ mem,
                            const float4* __restrict__ md,
                            float* __restrict__ out) {
    int idx = blockIdx.x * blockDim.x + threadIdx.x;
    float4* mem_out = (float4*)(out + OFF_MEM);   // 1KB offset, 16B aligned
    float4* md_out  = (float4*)(out + OFF_MD);
    if (idx < (M_LEN * D_OUT) / 4) mem_out[idx] = mem[idx];
    if (idx < (M_LEN * D_IN) / 4)  md_out[idx]  = md[idx];
    if (idx < B_ROWS) ((unsigned int*)out)[idx] = 0x7F800000u;  // +inf
}

// ---------------------------------------------------------------------------
// K1: enc = tanh(normalize(x) @ W1 + b1)   [256 x 256]
// one block per batch row, one thread per output column
// ---------------------------------------------------------------------------
__global__ __launch_bounds__(256) void k_enc(const float* __restrict__ x,
                                             const float* __restrict__ mean,
                                             const float* __restrict__ stdv,
                                             const float* __restrict__ W1,
                                             const float* __restrict__ b1,
                                             float* __restrict__ enc) {
    __shared__ float sx[D_IN];
    int b = blockIdx.x;
    int j = threadIdx.x;
    if (j < D_IN) {
        float s = stdv[j];
        float v = (s == 0.0f) ? 0.0f : (x[b * D_IN + j] - mean[j]) / s;
        sx[j] = v;
    }
    __syncthreads();
    float acc = b1[j];
#pragma unroll 8
    for (int k = 0; k < D_IN; ++k) {
        acc = fmaf(sx[k], W1[k * D_OUT + j], acc);
    }
    enc[b * D_OUT + j] = tanhf(acc);
}

// ---------------------------------------------------------------------------
// K2: loss[b] = min_m sum_d |enc[b,d] - memory[m,d]|
// GEMM-style tiling: 64 (b) x 64 (m) tile per block, k-chunks of 32.
// LDS tiles stored transposed [k][row] so the per-thread 4-wide micro-tile
// vectors are contiguous float4 reads.
// ---------------------------------------------------------------------------
#define TB 64
#define TM 64
#define TK 32

__global__ __launch_bounds__(256) void k_dist(const float* __restrict__ enc,
                                              const float* __restrict__ mem,
                                              float* __restrict__ out) {
    __shared__ __align__(16) float sE[TK][TB];  // [k][b]
    __shared__ __align__(16) float sM[TK][TM];  // [k][m]
    __shared__ float red[TB][17];

    const int mb = blockIdx.x;   // 0..63  memory tile
    const int bb = blockIdx.y;   // 0..3   batch tile
    const int t  = threadIdx.x;
    const int tr = t >> 4;       // 0..15  -> 4 b rows each
    const int tc = t & 15;       // 0..15  -> 4 m rows each
    const int b0 = bb * TB, m0 = mb * TM;

    float acc[4][4] = {};

    for (int k0 = 0; k0 < D_OUT; k0 += TK) {
        // stage: each tile is 64 rows x 32 cols = 512 float4; 2 per thread
#pragma unroll
        for (int f = t; f < 512; f += 256) {
            int row = f >> 3;        // 0..63
            int c4  = f & 7;         // 0..7
            int kl  = c4 * 4;
            float4 v = *(const float4*)(enc + (b0 + row) * D_OUT + k0 + kl);
            sE[kl + 0][row] = v.x; sE[kl + 1][row] = v.y;
            sE[kl + 2][row] = v.z; sE[kl + 3][row] = v.w;
            float4 w = *(const float4*)(mem + (m0 + row) * D_OUT + k0 + kl);
            sM[kl + 0][row] = w.x; sM[kl + 1][row] = w.y;
            sM[kl + 2][row] = w.z; sM[kl + 3][row] = w.w;
        }
        __syncthreads();

#pragma unroll
        for (int k = 0; k < TK; ++k) {
            float4 a  = *(const float4*)(&sE[k][tr * 4]);
            float4 bv = *(const float4*)(&sM[k][tc * 4]);
            float av[4] = {a.x, a.y, a.z, a.w};
            float bw[4] = {bv.x, bv.y, bv.z, bv.w};
#pragma unroll
            for (int i = 0; i < 4; ++i)
#pragma unroll
                for (int j = 0; j < 4; ++j)
                    acc[i][j] += fabsf(av[i] - bw[j]);
        }
        __syncthreads();
    }

    // per-thread min over its 4 m columns, per b row
#pragma unroll
    for (int i = 0; i < 4; ++i) {
        float m1 = fminf(fminf(acc[i][0], acc[i][1]),
                         fminf(acc[i][2], acc[i][3]));
        red[tr * 4 + i][tc] = m1;
    }
    __syncthreads();

    if (t < TB) {
        float m = red[t][0];
#pragma unroll
        for (int c = 1; c < 16; ++c) m = fminf(m, red[t][c]);
        // distances are >= 0, init is +inf -> uint bit-pattern atomicMin valid
        atomicMin((unsigned int*)out + (b0 + t), __float_as_uint(m));
    }
}

// ---------------------------------------------------------------------------
// K3: sequential circular-buffer scatter, collapsed to prefix-sum + scatter.
// count starts at M_LEN (memory full) so positions are prefix % M = prefix,
// all distinct since <=256 writes.
// ---------------------------------------------------------------------------
__global__ __launch_bounds__(256) void k_scatter(float* __restrict__ out,
                                                 const float* __restrict__ enc,
                                                 const float* __restrict__ x) {
    __shared__ int wcount[4];
    int t = threadIdx.x;
    float l = out[t];  // loss
    bool cond = isfinite(l) && (l <= BETA);
    unsigned long long m = __ballot(cond);
    int lane = t & 63;
    int wv   = t >> 6;
    int pre_in_wave = __popcll(m & ((1ull << lane) - 1ull));
    if (lane == 0) wcount[wv] = (int)__popcll(m);
    __syncthreads();
    int base = 0;
    for (int w = 0; w < wv; ++w) base += wcount[w];
    if (cond) {
        int pos = base + pre_in_wave;  // (M_LEN + prefix) % M_LEN
        float* mrow = out + OFF_MEM + pos * D_OUT;
        const float* erow = enc + t * D_OUT;
        for (int d = 0; d < D_OUT; ++d) mrow[d] = erow[d];
        float* drow = out + OFF_MD + pos * D_IN;
        const float* xrow = x + t * D_IN;
        for (int d = 0; d < D_IN; ++d) drow[d] = xrow[d];
    }
}

// ---------------------------------------------------------------------------
extern "C" void kernel_launch(void* const* d_in, const int* in_sizes, int n_in,
                              void* d_out, int out_size, void* d_ws, size_t ws_size,
                              hipStream_t stream) {
    const float* x      = (const float*)d_in[0];
    const float* mean   = (const float*)d_in[1];
    const float* stdv   = (const float*)d_in[2];
    const float* W1     = (const float*)d_in[3];
    const float* b1     = (const float*)d_in[4];
    const float* memory = (const float*)d_in[5];
    const float* memdat = (const float*)d_in[6];
    float* out = (float*)d_out;
    float* enc = (float*)d_ws;  // 256*256*4 = 256KB scratch

    // K0: output copies + loss init (independent of K1)
    k_init_copy<<<dim3((M_LEN * D_OUT / 4 + 255) / 256), dim3(256), 0, stream>>>(
        (const float4*)memory, (const float4*)memdat, out);

    // K1: encoder
    k_enc<<<dim3(B_ROWS), dim3(256), 0, stream>>>(x, mean, stdv, W1, b1, enc);

    // K2: L1 cdist + row min (atomicMin into loss)
    k_dist<<<dim3(M_LEN / TM, B_ROWS / TB), dim3(256), 0, stream>>>(enc, memory, out);

    // K3: prefix-sum scatter update
    k_scatter<<<dim3(1), dim3(256), 0, stream>>>(out, enc, x);
}